// Round 4
// baseline (609.121 us; speedup 1.0000x reference)
//
#include <hip/hip_runtime.h>

typedef unsigned short ushort_t;
typedef unsigned int   uint_t;
typedef __attribute__((ext_vector_type(8))) short  short8;
typedef __attribute__((ext_vector_type(4))) float  float4v;
typedef __attribute__((ext_vector_type(4))) uint_t uint4v;

#define B_    16
#define CIN_  320
#define COUT_ 320
#define NLORA 50
#define R_    4

// workspace layout (bytes)
#define XPAD_ELEMS ((size_t)B_ * 66 * 66 * CIN_)        // bf16 NHWC padded x
#define WB_OFF     (XPAD_ELEMS * 2)                     // base weights bf16 [9][320][320]
#define DB_OFF     (WB_OFF + (size_t)9 * 320 * 320 * 2) // per-b down bf16 [16][9][4][320]

__device__ __forceinline__ ushort_t bf16rne(float f) {
  uint_t u = __float_as_uint(f);
  u = (u + 0x7FFFu + ((u >> 16) & 1u)) >> 16;
  return (ushort_t)u;
}

#define GLDS16(gp, lp)                                                          \
  __builtin_amdgcn_global_load_lds(                                             \
      (const __attribute__((address_space(1))) void*)(gp),                      \
      (__attribute__((address_space(3))) void*)(lp), 16, 0, 0)

// lora_id int32/int64 detect + decode (first 64 B valid under either dtype)
__device__ __forceinline__ void lora_decode(const void* lora, int b, int* l_out,
                                            float* act_out) {
  const int* p32 = (const int*)lora;
  bool odd0 = true;
  #pragma unroll
  for (int i = 1; i < 16; i += 2) odd0 = odd0 && (p32[i] == 0);
  long long raw = odd0 ? ((const long long*)lora)[b] : (long long)p32[b];
  long long idx = (raw >= 0) ? (raw >> 2) : -(((-raw) + 3) >> 2);   // floor/4
  *act_out = (idx >= 0) ? 1.0f : 0.0f;                              // SCALE==1 folded
  *l_out = (int)(idx < 0 ? 0 : (idx > (NLORA - 1) ? (NLORA - 1) : idx));
}

// ---------------------------------------------------------------------------
// Kernel 1: x [B][C][H][W] fp32 -> x_pad [B][66][66][C] bf16 (interior),
// with halo zeroing fused (edge pixels per row; full rows 0/65 by h==0 blocks).
// ---------------------------------------------------------------------------
__global__ __launch_bounds__(256)
void pad_convert(const float* __restrict__ x, ushort_t* __restrict__ x_pad) {
  __shared__ float t[64][65];
  const int cc  = blockIdx.x;   // channel chunk 0..4 (64 ch)
  const int h   = blockIdx.y;   // 0..63
  const int b   = blockIdx.z;
  const int tid = threadIdx.x;

  // fused halo zeroing (disjoint addresses; no sync needed)
  if (tid < 16) {               // edge pixels w=0 / w=65 of row h+1
    int w65 = (tid >> 3) * 65;
    int ch8 = tid & 7;
    *(uint4v*)(x_pad + (((size_t)(b * 66 + h + 1)) * 66 + w65) * CIN_ + cc * 64 + ch8 * 8)
        = (uint4v)0u;
  }
  if (h == 0) {                 // full rows 0 and 65 for this cc chunk
    for (int g = tid; g < 1056; g += 256) {
      int rr  = (g >= 528) ? 65 : 0;
      int rem = (g >= 528) ? g - 528 : g;
      int w   = rem >> 3;
      int ch8 = rem & 7;
      *(uint4v*)(x_pad + (((size_t)(b * 66 + rr)) * 66 + w) * CIN_ + cc * 64 + ch8 * 8)
          = (uint4v)0u;
    }
  }

  #pragma unroll
  for (int it = 0; it < 4; ++it) {
    int g  = it * 256 + tid;
    int cl = g >> 4, w4 = (g & 15) * 4;
    float4v v = *(const float4v*)(x +
        (((size_t)(b * CIN_ + cc * 64 + cl)) * 64 + h) * 64 + w4);
    t[cl][w4 + 0] = v.x; t[cl][w4 + 1] = v.y;
    t[cl][w4 + 2] = v.z; t[cl][w4 + 3] = v.w;
  }
  __syncthreads();
  #pragma unroll
  for (int it = 0; it < 2; ++it) {
    int g   = it * 256 + tid;
    int ch8 = g & 7;
    int w   = g >> 3;
    uint4v p;
    p.x = (uint_t)bf16rne(t[ch8 * 8 + 0][w]) | ((uint_t)bf16rne(t[ch8 * 8 + 1][w]) << 16);
    p.y = (uint_t)bf16rne(t[ch8 * 8 + 2][w]) | ((uint_t)bf16rne(t[ch8 * 8 + 3][w]) << 16);
    p.z = (uint_t)bf16rne(t[ch8 * 8 + 4][w]) | ((uint_t)bf16rne(t[ch8 * 8 + 5][w]) << 16);
    p.w = (uint_t)bf16rne(t[ch8 * 8 + 6][w]) | ((uint_t)bf16rne(t[ch8 * 8 + 7][w]) << 16);
    *(uint4v*)(x_pad + (((size_t)(b * 66 + h + 1)) * 66 + (w + 1)) * CIN_ + cc * 64 + ch8 * 8) = p;
  }
}

// ---------------------------------------------------------------------------
// Kernel 2: weight prep (fused). Blocks 0..319: Wb[tap][o][c] = bf16(conv_w).
// Blocks 320..335: Db[b][tap][r][c] = bf16(down_w[l]).
// ---------------------------------------------------------------------------
__global__ __launch_bounds__(320)
void prep_weights(const float* __restrict__ conv_w, const float* __restrict__ down_w,
                  const void* __restrict__ lora,
                  ushort_t* __restrict__ Wb, ushort_t* __restrict__ Db) {
  const int bid = blockIdx.x;
  const int c   = threadIdx.x;   // 0..319
  if (bid < 320) {
    __shared__ __align__(16) float lw[2880];
    const int o = bid;
    const float4v* src = (const float4v*)(conv_w + (size_t)o * 2880);
    for (int g = c; g < 720; g += 320) ((float4v*)lw)[g] = src[g];
    __syncthreads();
    #pragma unroll
    for (int tap = 0; tap < 9; ++tap)
      Wb[((size_t)tap * COUT_ + o) * CIN_ + c] = bf16rne(lw[c * 9 + tap]);
  } else {
    const int b = bid - 320;
    int l; float act;
    lora_decode(lora, b, &l, &act);
    #pragma unroll
    for (int r = 0; r < R_; ++r)
      #pragma unroll
      for (int tap = 0; tap < 9; ++tap)
        Db[(((size_t)b * 9 + tap) * R_ + r) * CIN_ + c] =
            bf16rne(down_w[(size_t)l * 11520 + r * 2880 + c * 9 + tap]);
  }
}

// ---------------------------------------------------------------------------
// Kernel 3: implicit-GEMM conv, bf16 MFMA 16x16x32, fp32-acc, streamed-B.
// 512 thr (8 waves). Tile: BM=256 (4 output rows x 64 cols), BN=80 out-ch.
// Wave wv: row = wv>>1, col-half = wv&1 -> 2 m-subs x 5 n-subs (40 acc VGPRs)
// + rank-4 LoRA down-proj MFMA per m-sub (8 VGPRs).
// x staged to LDS via global_load_lds (25 KB only); base weights Wb (1.84 MB,
// L2-resident in every XCD) loaded per-lane straight to registers -> no wt
// LDS, no weight-staging barrier traffic, no dependence on XCD mapping.
// Grid 1024, n-tiles fastest (adjacent ids share the x-tile).
// ---------------------------------------------------------------------------
__global__ __launch_bounds__(512, 4)
void conv_main(const ushort_t* __restrict__ x_pad, const ushort_t* __restrict__ Wb,
               const ushort_t* __restrict__ Db, const float* __restrict__ conv_b,
               const float* __restrict__ up_w, const void* __restrict__ lora,
               float* __restrict__ out) {
  __shared__ __align__(16) ushort_t xs[12672];  // [6][66][4 slot][8ch] 25344 B
  __shared__ __align__(16) ushort_t wd[1152];   // [9 tap][4 r][4 slot][8ch] 2304 B
  __shared__ __align__(16) ushort_t zz[32];     // 64 B zeros

  const int tid = threadIdx.x;
  const int id  = blockIdx.x;          // 0..1023
  const int o0  = (id & 3) * 80;       // n-tile (fastest -> shared x among ids)
  const int h0  = ((id >> 2) & 15) * 4;
  const int b   = id >> 6;

  const int wv   = tid >> 6;           // 0..7
  const int row  = wv >> 1;            // output row h0+row
  const int half = wv & 1;             // col half (0..31 / 32..63)
  const int la   = tid & 15;
  const int q    = (tid >> 4) & 3;

  if (tid < 4) ((uint4v*)zz)[tid] = (uint4v)0u;

  // x staging source offsets (elements, sans c0)
  int xoff[4];
  #pragma unroll
  for (int it = 0; it < 4; ++it) {
    int g  = tid + it * 512;
    int hh = g / 264;
    int r  = g - hh * 264;
    int ww = r >> 2;
    int s  = r & 3;
    xoff[it] = ((b * 66 + h0 + hh) * 66 + ww) * CIN_ + (((s ^ (ww >> 1)) & 3) * 8);
  }
  int dwoff = 0;
  if (tid < 144)
    dwoff = (((b * 9 + (tid >> 4)) * R_) + ((tid >> 2) & 3)) * CIN_ + (tid & 3) * 8;

  // per-lane streamed-B base: o = o0 + j*16 + la, c-chunk = q (j,tap via consts)
  const ushort_t* wptr = Wb + (size_t)(o0 + la) * CIN_ + q * 8;

  float4v acc[2][5];
  float4v acc_d[2];
  #pragma unroll
  for (int i = 0; i < 2; ++i) {
    acc_d[i] = (float4v)0.0f;
    #pragma unroll
    for (int j = 0; j < 5; ++j) acc[i][j] = (float4v)0.0f;
  }

  for (int c0 = 0; c0 < CIN_; c0 += 32) {
    __syncthreads();   // previous chunk consumed
    #pragma unroll
    for (int it = 0; it < 4; ++it) {
      int g = tid + it * 512;
      if (it < 3 || g < 1584) GLDS16(x_pad + xoff[it] + c0, xs + g * 8);
    }
    if (tid < 144) GLDS16(Db + dwoff + c0, wd + tid * 8);
    __syncthreads();   // staged data visible

    const ushort_t* wc = wptr + c0;
    #pragma unroll
    for (int tap = 0; tap < 9; ++tap) {
      const int kh = tap / 3, kw = tap % 3;
      short8 bfr[5];
      #pragma unroll
      for (int j = 0; j < 5; ++j)
        bfr[j] = *(const short8*)(wc + tap * (COUT_ * CIN_) + j * 16 * CIN_);
      short8 bdv = *(const short8*)(wd + ((tap * 4 + (la & 3)) * 4 + q) * 8);
      short8 bd  = (la < 4) ? bdv : *(const short8*)zz;
      const int hh = row + kh;
      #pragma unroll
      for (int i = 0; i < 2; ++i) {
        int ww = half * 32 + i * 16 + la + kw;
        short8 af = *(const short8*)(xs + ((hh * 66 + ww) * 4 + ((q ^ (ww >> 1)) & 3)) * 8);
        #pragma unroll
        for (int j = 0; j < 5; ++j)
          acc[i][j] = __builtin_amdgcn_mfma_f32_16x16x32_bf16(af, bfr[j], acc[i][j], 0, 0, 0);
        acc_d[i] = __builtin_amdgcn_mfma_f32_16x16x32_bf16(af, bd, acc_d[i], 0, 0, 0);
      }
    }
  }

  // ---- LoRA: acc += up[o,r] * down_acc[r] (cross-lane gather of acc_d)
  int l; float act;
  lora_decode(lora, b, &l, &act);
  float4v upv[5];
  #pragma unroll
  for (int j = 0; j < 5; ++j) {
    int o = o0 + j * 16 + la;
    upv[j] = act * (*(const float4v*)(up_w + ((size_t)l * COUT_ + o) * R_));
  }
  #pragma unroll
  for (int i = 0; i < 2; ++i) {
    float yd[4][4];   // [r][reg]
    #pragma unroll
    for (int rp = 0; rp < 4; ++rp)
      #pragma unroll
      for (int r = 0; r < 4; ++r)
        yd[r][rp] = __shfl(acc_d[i][rp], (q << 4) + r, 64);
    #pragma unroll
    for (int j = 0; j < 5; ++j)
      #pragma unroll
      for (int rp = 0; rp < 4; ++rp)
        acc[i][j][rp] += upv[j].x * yd[0][rp] + upv[j].y * yd[1][rp]
                       + upv[j].z * yd[2][rp] + upv[j].w * yd[3][rp];
  }

  // ---- Epilogue: direct stores. Per o each wave covers a contiguous 128 B
  // half-row (lanes q x regs x i) -> full-line write combining in L2.
  #pragma unroll
  for (int j = 0; j < 5; ++j) {
    const int o = o0 + j * 16 + la;
    const float bias = conv_b[o];
    #pragma unroll
    for (int i = 0; i < 2; ++i) {
      float4v v = acc[i][j];
      v += bias;
      const int m = half * 32 + i * 16 + q * 4;
      *(float4v*)(out + (size_t)(b * COUT_ + o) * 4096 + (h0 + row) * 64 + m) = v;
    }
  }
}

// ---------------------------------------------------------------------------
extern "C" void kernel_launch(void* const* d_in, const int* in_sizes, int n_in,
                              void* d_out, int out_size, void* d_ws, size_t ws_size,
                              hipStream_t stream) {
  const float* x      = (const float*)d_in[0];
  const float* conv_w = (const float*)d_in[1];
  const float* conv_b = (const float*)d_in[2];
  const float* down_w = (const float*)d_in[3];
  const float* up_w   = (const float*)d_in[4];
  const void*  lora   = d_in[5];
  float* out = (float*)d_out;

  ushort_t* x_pad = (ushort_t*)d_ws;
  ushort_t* Wb    = (ushort_t*)((char*)d_ws + WB_OFF);
  ushort_t* Db    = (ushort_t*)((char*)d_ws + DB_OFF);

  pad_convert  <<<dim3(5, 64, 16), 256, 0, stream>>>(x, x_pad);
  prep_weights <<<dim3(336),       320, 0, stream>>>(conv_w, down_w, lora, Wb, Db);
  conv_main    <<<dim3(1024),      512, 0, stream>>>(x_pad, Wb, Db, conv_b,
                                                     up_w, lora, out);
}